// Round 3
// baseline (312.166 us; speedup 1.0000x reference)
//
#include <hip/hip_runtime.h>
#include <hip/hip_cooperative_groups.h>

namespace cg = cooperative_groups;

#define B 2
#define L 2048
#define C 256
#define H 8
#define D 32
#define HB 16          // H*B
#define GRID 512
#define SCALE 0.17677669529663687f  // 1/sqrt(32)

using bf16x8 = __attribute__((ext_vector_type(8))) __bf16;
using f32x4  = __attribute__((ext_vector_type(4))) float;

// round-to-nearest-even f32 -> bf16 bits
static __device__ inline unsigned short f2bf(float f) {
    unsigned u = __float_as_uint(f);
    return (unsigned short)((u + 0x7fffu + ((u >> 16) & 1u)) >> 16);
}

// ---------------------------------------------------------------------------
// Single cooperative kernel, 512 blocks x 256 threads, 2 blocks/CU resident.
// Phase 1: projections (8 token-rows/block) -> Q,K bf16 (pre-scaled Q), V f32
// Phase 2: l_q = sum_k exp(s_qk) over FULL row (mask is post-softmax);
//          G = V/l.  Block = 64 queries; wave holds 4 Q-frags, each K-frag
//          load feeds 4 MFMAs.
// Phase 3: S[k] = sum_{q>=k} G[q] exp(s_qk).  Wave owns k-tile w*32+kB
//          (striped for load balance), iterates q-tiles >= diagonal.
// Phase 4: W=3 SAME avg-pool along k (pad-excluded counts) -> (B,L,H).
// ---------------------------------------------------------------------------
__global__ __launch_bounds__(256, 2) void fused_kernel(
    const float* __restrict__ x,   // (B,L,C)
    const float* __restrict__ Wq,  // (C, H*D)
    const float* __restrict__ bq,  // (H,1,1,D)
    const float* __restrict__ Wk,
    const float* __restrict__ bk,
    const float* __restrict__ Wv,  // (C, H)
    const float* __restrict__ pe,  // (L, C)
    unsigned short* __restrict__ Qo,  // (HB,L,D) bf16 bits
    unsigned short* __restrict__ Ko,  // (HB,L,D) bf16 bits
    float* __restrict__ Vo,           // (HB,L)
    float* __restrict__ G,            // (HB,L)
    float* __restrict__ S,            // (HB,L)
    float* __restrict__ out)          // (B,L,H)
{
    cg::grid_group grid = cg::this_grid();

    __shared__ float xqT[C][8];               // 8 KiB
    __shared__ float xrT[C][8];               // 8 KiB
    __shared__ float vred[4][8][8];           // 1 KiB
    __shared__ float lred[4][4][4][4][16];    // 16 KiB [wave][frag][quad][reg][col]

    const int t = threadIdx.x;
    const int blk = blockIdx.x;

    // ================= Phase 1: projections =================
    {
        const int row0 = blk * 8;
        const int b = row0 >> 11;   // 8-row block never straddles batches

#pragma unroll
        for (int i = 0; i < 8; ++i) {
            const int row = row0 + i;
            const int l = row & (L - 1);
            const float xv = x[row * C + t];
            xrT[t][i] = xv;
            xqT[t][i] = xv + pe[l * C + t];
        }
        __syncthreads();

        float accq[8], acck[8];
#pragma unroll
        for (int i = 0; i < 8; ++i) { accq[i] = 0.f; acck[i] = 0.f; }

#pragma unroll 4
        for (int c = 0; c < C; ++c) {
            const float wq = Wq[c * (H * D) + t];
            const float wk = Wk[c * (H * D) + t];
            const float4 xa = *(const float4*)&xqT[c][0];
            const float4 xb = *(const float4*)&xqT[c][4];
            accq[0] += xa.x * wq; acck[0] += xa.x * wk;
            accq[1] += xa.y * wq; acck[1] += xa.y * wk;
            accq[2] += xa.z * wq; acck[2] += xa.z * wk;
            accq[3] += xa.w * wq; acck[3] += xa.w * wk;
            accq[4] += xb.x * wq; acck[4] += xb.x * wk;
            accq[5] += xb.y * wq; acck[5] += xb.y * wk;
            accq[6] += xb.z * wq; acck[6] += xb.z * wk;
            accq[7] += xb.w * wq; acck[7] += xb.w * wk;
        }

        const int h = t >> 5, d = t & 31;
        const float bqv = bq[t];
        const float bkv = bk[t];
#pragma unroll
        for (int i = 0; i < 8; ++i) {
            const int l = (row0 + i) & (L - 1);
            const size_t o = ((size_t)(h * B + b) * L + l) * D + d;
            Qo[o] = f2bf((accq[i] + bqv) * SCALE);
            Ko[o] = f2bf(acck[i] + bkv);
        }

        // V gate: 4 waves split C, LDS-reduce.
        {
            const int cc = t >> 6, sub = t & 63, vi = sub >> 3, vh = sub & 7;
            float va = 0.f;
            for (int c = cc * 64; c < cc * 64 + 64; ++c)
                va += xrT[c][vi] * Wv[c * H + vh];
            vred[cc][vi][vh] = va;
        }
        __syncthreads();
        if (t < 64) {
            const int i2 = t >> 3, h2 = t & 7;
            const float v = vred[0][i2][h2] + vred[1][i2][h2] +
                            vred[2][i2][h2] + vred[3][i2][h2];
            const int l = (row0 + i2) & (L - 1);
            Vo[(h2 * B + b) * L + l] = v;
        }
    }
    grid.sync();

    // ================= Phase 2: softmax denominators -> G =================
    {
        const int hb = blk >> 5, qb = blk & 31;
        const int w = t >> 6, lane = t & 63;
        const int quad = lane >> 4, col = lane & 15;
        const __bf16* Qp = (const __bf16*)Qo + (size_t)hb * L * D;
        const __bf16* Kp = (const __bf16*)Ko + (size_t)hb * L * D;

        bf16x8 qf[4];
#pragma unroll
        for (int f = 0; f < 4; ++f)
            qf[f] = *(const bf16x8*)(Qp + ((qb * 4 + f) * 16 + col) * D + quad * 8);

        const f32x4 zero = {0.f, 0.f, 0.f, 0.f};
        float lsum[4][4];
#pragma unroll
        for (int f = 0; f < 4; ++f)
#pragma unroll
            for (int r = 0; r < 4; ++r) lsum[f][r] = 0.f;

#pragma unroll 2
        for (int kt = 0; kt < 32; ++kt) {
            const bf16x8 kf =
                *(const bf16x8*)(Kp + ((w * 32 + kt) * 16 + col) * D + quad * 8);
#pragma unroll
            for (int f = 0; f < 4; ++f) {
                f32x4 a = __builtin_amdgcn_mfma_f32_16x16x32_bf16(qf[f], kf, zero, 0, 0, 0);
                lsum[f][0] += __expf(a[0]);
                lsum[f][1] += __expf(a[1]);
                lsum[f][2] += __expf(a[2]);
                lsum[f][3] += __expf(a[3]);
            }
        }
#pragma unroll
        for (int f = 0; f < 4; ++f)
#pragma unroll
            for (int r = 0; r < 4; ++r) lred[w][f][quad][r][col] = lsum[f][r];
        __syncthreads();
        if (t < 64) {  // q_local = t = f*16 + qd*4 + r
            const int f = t >> 4, qd = (t >> 2) & 3, r = t & 3;
            float s = 0.f;
#pragma unroll
            for (int w2 = 0; w2 < 4; ++w2) {
                const float* p = &lred[w2][f][qd][r][0];
#pragma unroll
                for (int c2 = 0; c2 < 16; ++c2) s += p[c2];
            }
            const int qq = hb * L + qb * 64 + t;
            G[qq] = Vo[qq] / s;
        }
    }
    grid.sync();

    // ================= Phase 3: masked gated sums -> S =================
    {
        const int hb = blk >> 5, kB = blk & 31;
        const int w = t >> 6, lane = t & 63;
        const int quad = lane >> 4, col = lane & 15;
        const __bf16* Qp = (const __bf16*)Qo + (size_t)hb * L * D;
        const __bf16* Kp = (const __bf16*)Ko + (size_t)hb * L * D;
        const float* Gp = G + hb * L;

        const int kt16 = w * 32 + kB;   // striped k-tile for load balance
        const bf16x8 kf = *(const bf16x8*)(Kp + (kt16 * 16 + col) * D + quad * 8);
        const f32x4 zero = {0.f, 0.f, 0.f, 0.f};
        const int kidx = kt16 * 16 + col;

        float sacc = 0.f;
        for (int qt = kt16; qt < 128; ++qt) {
            const bf16x8 qf = *(const bf16x8*)(Qp + (qt * 16 + col) * D + quad * 8);
            f32x4 a = __builtin_amdgcn_mfma_f32_16x16x32_bf16(qf, kf, zero, 0, 0, 0);
            const float4 g = *(const float4*)(Gp + qt * 16 + quad * 4);
            const int qbase = qt * 16 + quad * 4;
            sacc += (qbase + 0 >= kidx) ? __expf(a[0]) * g.x : 0.f;
            sacc += (qbase + 1 >= kidx) ? __expf(a[1]) * g.y : 0.f;
            sacc += (qbase + 2 >= kidx) ? __expf(a[2]) * g.z : 0.f;
            sacc += (qbase + 3 >= kidx) ? __expf(a[3]) * g.w : 0.f;
        }
        // sum across the 4 quads (same col) in-register
        sacc += __shfl_xor(sacc, 16, 64);
        sacc += __shfl_xor(sacc, 32, 64);
        if (lane < 16) S[hb * L + kt16 * 16 + lane] = sacc;
    }
    grid.sync();

    // ================= Phase 4: W=3 avg-pool + layout =================
    if (t < 64) {
        const int flat = blk * 64 + t;          // (b*L + k)*H + h
        const int h = flat & 7;
        const int k = (flat >> 3) & (L - 1);
        const int b = flat >> 14;
        const float* Sb = S + (h * B + b) * L;
        float s = Sb[k];
        float cnt = 1.f;
        if (k > 0)     { s += Sb[k - 1]; cnt += 1.f; }
        if (k < L - 1) { s += Sb[k + 1]; cnt += 1.f; }
        out[flat] = s / cnt;
    }
}

// ---------------------------------------------------------------------------
extern "C" void kernel_launch(void* const* d_in, const int* in_sizes, int n_in,
                              void* d_out, int out_size, void* d_ws, size_t ws_size,
                              hipStream_t stream)
{
    const float* x  = (const float*)d_in[0];
    const float* Wq = (const float*)d_in[1];
    const float* bq = (const float*)d_in[2];
    const float* Wk = (const float*)d_in[3];
    const float* bk = (const float*)d_in[4];
    const float* Wv = (const float*)d_in[5];
    const float* pe = (const float*)d_in[6];
    float* out = (float*)d_out;

    unsigned short* Qbf = (unsigned short*)d_ws;        // 1,048,576 bf16 (2 MB)
    unsigned short* Kbf = Qbf + (size_t)HB * L * D;     // 2 MB
    float* Vo = (float*)(Kbf + (size_t)HB * L * D);     // 32768 f32
    float* G  = Vo + (size_t)HB * L;                    // 32768 f32
    float* S  = G  + (size_t)HB * L;                    // 32768 f32

    void* args[] = {
        (void*)&x, (void*)&Wq, (void*)&bq, (void*)&Wk, (void*)&bk,
        (void*)&Wv, (void*)&pe, (void*)&Qbf, (void*)&Kbf, (void*)&Vo,
        (void*)&G, (void*)&S, (void*)&out
    };
    hipLaunchCooperativeKernel((const void*)fused_kernel, dim3(GRID), dim3(256),
                               args, 0, stream);
}

// Round 6
// 142.109 us; speedup vs baseline: 2.1967x; 2.1967x over previous
//
#include <hip/hip_runtime.h>

#define B 2
#define L 2048
#define C 256
#define H 8
#define D 32
#define HB 16   // H*B
// 1/sqrt(32) * log2(e): scores computed in log2 domain so exp() is a bare
// v_exp_f32 (exp2). Softmax is invariant to the consistent rescale.
#define SCALE2 0.25503486f

using bf16x8 = __attribute__((ext_vector_type(8))) __bf16;
using f32x4  = __attribute__((ext_vector_type(4))) float;

// bare v_exp_f32 (2^x)
static __device__ inline float fexp2(float x) {
    return __builtin_amdgcn_exp2f(x);
}

// round-to-nearest-even f32 -> bf16 bits
static __device__ inline unsigned short f2bf(float f) {
    unsigned u = __float_as_uint(f);
    return (unsigned short)((u + 0x7fffu + ((u >> 16) & 1u)) >> 16);
}

// ---------------------------------------------------------------------------
// Kernel 1: prep. grid = 4096/16 = 256 blocks, 256 threads.
//  a) xq_bf[row][c] = bf16(x[row][c] + pe[l][c])           (GEMM A matrix)
//  b) V[h,b,l] = sum_c x * Wv   (fp32, exact)
//  c) WqkT[n][c] = bf16(n<256 ? Wq[c][n] : Wk[c][n-256])   (GEMM B matrix,
//     n-major as the MFMA B-fragment wants; block g transposes column c=g)
// ---------------------------------------------------------------------------
__global__ __launch_bounds__(256) void prep_kernel(
    const float* __restrict__ x,   // (B,L,C)
    const float* __restrict__ Wq,  // (C, 256)
    const float* __restrict__ Wk,  // (C, 256)
    const float* __restrict__ Wv,  // (C, H)
    const float* __restrict__ pe,  // (L, C)
    unsigned short* __restrict__ xq_bf,  // (4096, 256) bf16
    unsigned short* __restrict__ WqkT,   // (512, 256) bf16
    float* __restrict__ Vo)              // (HB, L)
{
    __shared__ float xsh[16][C];   // 16 KiB
    const int t = threadIdx.x;
    const int row0 = blockIdx.x * 16;
    const int b = row0 >> 11;      // 16-row block never straddles batches

#pragma unroll
    for (int i = 0; i < 16; ++i) {
        const int row = row0 + i;
        const int l = row & (L - 1);
        const float xv = x[row * C + t];
        xsh[i][t] = xv;
        xq_bf[row * C + t] = f2bf(xv + pe[l * C + t]);
    }

    // c) weight transpose: c = blockIdx.x, n = t and t+256
    {
        const int c = blockIdx.x;
        WqkT[t * C + c]         = f2bf(Wq[c * 256 + t]);
        WqkT[(t + 256) * C + c] = f2bf(Wk[c * 256 + t]);
    }
    __syncthreads();

    // b) V gate (threads 0..127: i = t>>3, h = t&7)
    if (t < 128) {
        const int i = t >> 3, h = t & 7;
        float acc = 0.f;
#pragma unroll 4
        for (int c = 0; c < C; ++c) acc += xsh[i][c] * Wv[c * H + h];
        const int l = (row0 + i) & (L - 1);
        Vo[(h * B + b) * L + l] = acc;
    }
}

// ---------------------------------------------------------------------------
// Kernel 2: QK projection GEMM via MFMA.
// Y(4096 x 512) = xq_bf(4096 x 256) @ WqkT(512 x 256)^T.
// grid = (4096/64) x (512/64) = 512 blocks; wave w does rows [m0+16w, +16),
// all 64 cols of the block. Epilogue: +bias, (Q only) *SCALE2, ->bf16,
// scatter to (h*B+b, l, d) layout.
// ---------------------------------------------------------------------------
__global__ __launch_bounds__(256) void qkgemm_kernel(
    const __bf16* __restrict__ A,     // (4096, 256)
    const __bf16* __restrict__ Bw,    // (512, 256)
    const float* __restrict__ bq,     // (256,) flat h*D+d
    const float* __restrict__ bk,
    unsigned short* __restrict__ Qo,  // (HB, L, D) bf16
    unsigned short* __restrict__ Ko)  // (HB, L, D) bf16
{
    const int t = threadIdx.x;
    const int w = t >> 6, lane = t & 63;
    const int quad = lane >> 4, col = lane & 15;
    const int m0 = (blockIdx.x >> 3) * 64 + w * 16;
    const int n0 = (blockIdx.x & 7) * 64;

    const f32x4 zero = {0.f, 0.f, 0.f, 0.f};
    f32x4 acc[4] = {zero, zero, zero, zero};

#pragma unroll
    for (int ks = 0; ks < 8; ++ks) {
        const int c0 = ks * 32 + quad * 8;
        const bf16x8 af = *(const bf16x8*)(A + (m0 + col) * C + c0);
#pragma unroll
        for (int j = 0; j < 4; ++j) {
            const bf16x8 bf =
                *(const bf16x8*)(Bw + (n0 + j * 16 + col) * C + c0);
            acc[j] = __builtin_amdgcn_mfma_f32_16x16x32_bf16(af, bf, acc[j], 0, 0, 0);
        }
    }

#pragma unroll
    for (int j = 0; j < 4; ++j) {
        const int n_g = n0 + j * 16 + col;       // D col = lane&15
        const bool isQ = n_g < 256;              // wave-uniform (16-col groups)
        const int n2 = isQ ? n_g : n_g - 256;
        const int h = n2 >> 5, d = n2 & 31;
        const float bias = isQ ? bq[n2] : bk[n2];
        unsigned short* dst = isQ ? Qo : Ko;
#pragma unroll
        for (int r = 0; r < 4; ++r) {
            const int m_g = m0 + quad * 4 + r;   // D row = quad*4+r
            const int b = m_g >> 11, l = m_g & (L - 1);
            float v = acc[j][r] + bias;
            if (isQ) v *= SCALE2;
            dst[((size_t)(h * B + b) * L + l) * D + d] = f2bf(v);
        }
    }
}

// ---------------------------------------------------------------------------
// Kernel 3 (pass A): l_q = sum over ALL k of exp2(s_qk)  (mask is
// post-softmax); G = V / l.  grid = HB * (L/32) = 1024 blocks (4 blocks/CU).
// Block = 32 queries (2 Q-frags/wave); waves split the 128 k-tiles 4 ways;
// each K-frag load feeds 2 MFMAs.
// ---------------------------------------------------------------------------
__global__ __launch_bounds__(256) void passA_kernel(
    const __bf16* __restrict__ Qb, const __bf16* __restrict__ Kb,
    const float* __restrict__ V, float* __restrict__ G)
{
    __shared__ float lred[4][2][4][4][16];  // 8 KiB [wave][frag][quad][reg][col]
    const int t = threadIdx.x;
    const int w = t >> 6, lane = t & 63;
    const int quad = lane >> 4, col = lane & 15;
    const int hb = blockIdx.x >> 6, qb = blockIdx.x & 63;
    const __bf16* Qp = Qb + (size_t)hb * L * D;
    const __bf16* Kp = Kb + (size_t)hb * L * D;

    bf16x8 qf[2];
#pragma unroll
    for (int f = 0; f < 2; ++f)
        qf[f] = *(const bf16x8*)(Qp + ((qb * 2 + f) * 16 + col) * D + quad * 8);

    const f32x4 zero = {0.f, 0.f, 0.f, 0.f};
    float lsum[2][4];
#pragma unroll
    for (int f = 0; f < 2; ++f)
#pragma unroll
        for (int r = 0; r < 4; ++r) lsum[f][r] = 0.f;

#pragma unroll 4
    for (int kt = 0; kt < 32; ++kt) {
        const bf16x8 kf =
            *(const bf16x8*)(Kp + ((w * 32 + kt) * 16 + col) * D + quad * 8);
#pragma unroll
        for (int f = 0; f < 2; ++f) {
            f32x4 a = __builtin_amdgcn_mfma_f32_16x16x32_bf16(qf[f], kf, zero, 0, 0, 0);
            lsum[f][0] += fexp2(a[0]);
            lsum[f][1] += fexp2(a[1]);
            lsum[f][2] += fexp2(a[2]);
            lsum[f][3] += fexp2(a[3]);
        }
    }
#pragma unroll
    for (int f = 0; f < 2; ++f)
#pragma unroll
        for (int r = 0; r < 4; ++r) lred[w][f][quad][r][col] = lsum[f][r];
    __syncthreads();
    if (t < 32) {   // q_local = t = f*16 + qd*4 + r
        const int f = t >> 4, rem = t & 15, qd = rem >> 2, r = rem & 3;
        float s = 0.f;
#pragma unroll
        for (int w2 = 0; w2 < 4; ++w2) {
            const float* p = &lred[w2][f][qd][r][0];
#pragma unroll
            for (int c2 = 0; c2 < 16; ++c2) s += p[c2];
        }
        const int qq = hb * L + qb * 32 + t;
        G[qq] = V[qq] / s;
    }
}

// ---------------------------------------------------------------------------
// Kernel 4 (pass B): S[k] = sum_{q>=k} G[q] * exp2(s_qk).
// grid = HB * (L/16) = 2048 blocks (8 blocks/CU); block owns one 16-key
// tile, 4 waves stripe the q-tiles >= the diagonal.
// Reduction: quad-shuffle within wave, then LDS across the 4 waves
// (round-4 BUG was dropping the cross-wave sum).
// ---------------------------------------------------------------------------
__global__ __launch_bounds__(256) void passB_kernel(
    const __bf16* __restrict__ Qb, const __bf16* __restrict__ Kb,
    const float* __restrict__ G, float* __restrict__ S)
{
    __shared__ float sred[4][16];
    const int t = threadIdx.x;
    const int w = t >> 6, lane = t & 63;
    const int quad = lane >> 4, col = lane & 15;
    const int kt = blockIdx.x & 127, hb = blockIdx.x >> 7;
    const __bf16* Qp = Qb + (size_t)hb * L * D;
    const __bf16* Kp = Kb + (size_t)hb * L * D;
    const float* Gp = G + hb * L;

    const bf16x8 kf = *(const bf16x8*)(Kp + (kt * 16 + col) * D + quad * 8);
    const f32x4 zero = {0.f, 0.f, 0.f, 0.f};
    const int kidx = kt * 16 + col;

    float sacc = 0.f;
    for (int qt = kt + w; qt < 128; qt += 4) {
        const bf16x8 qf = *(const bf16x8*)(Qp + (qt * 16 + col) * D + quad * 8);
        f32x4 a = __builtin_amdgcn_mfma_f32_16x16x32_bf16(qf, kf, zero, 0, 0, 0);
        const float4 g = *(const float4*)(Gp + qt * 16 + quad * 4);
        const int qbase = qt * 16 + quad * 4;
        sacc += (qbase + 0 >= kidx) ? fexp2(a[0]) * g.x : 0.f;
        sacc += (qbase + 1 >= kidx) ? fexp2(a[1]) * g.y : 0.f;
        sacc += (qbase + 2 >= kidx) ? fexp2(a[2]) * g.z : 0.f;
        sacc += (qbase + 3 >= kidx) ? fexp2(a[3]) * g.w : 0.f;
    }
    sacc += __shfl_xor(sacc, 16, 64);   // sum the 4 quads (same col)
    sacc += __shfl_xor(sacc, 32, 64);
    if (lane < 16) sred[w][lane] = sacc;
    __syncthreads();
    if (t < 16)
        S[hb * L + kt * 16 + t] =
            sred[0][t] + sred[1][t] + sred[2][t] + sred[3][t];
}

// ---------------------------------------------------------------------------
// Kernel 5: W=3 SAME avg-pool along k (pad-excluded counts) + layout
// transform to (B, L, H).
// ---------------------------------------------------------------------------
__global__ __launch_bounds__(256) void pool_kernel(
    const float* __restrict__ S, float* __restrict__ out)
{
    const int flat = blockIdx.x * 256 + threadIdx.x;  // (b*L + k)*H + h
    const int h = flat & 7;
    const int k = (flat >> 3) & (L - 1);
    const int b = flat >> 14;
    const float* Sb = S + (h * B + b) * L;
    float s = Sb[k];
    float cnt = 1.f;
    if (k > 0)     { s += Sb[k - 1]; cnt += 1.f; }
    if (k < L - 1) { s += Sb[k + 1]; cnt += 1.f; }
    out[flat] = s / cnt;
}

// ---------------------------------------------------------------------------
extern "C" void kernel_launch(void* const* d_in, const int* in_sizes, int n_in,
                              void* d_out, int out_size, void* d_ws, size_t ws_size,
                              hipStream_t stream)
{
    const float* x  = (const float*)d_in[0];
    const float* Wq = (const float*)d_in[1];
    const float* bq = (const float*)d_in[2];
    const float* Wk = (const float*)d_in[3];
    const float* bk = (const float*)d_in[4];
    const float* Wv = (const float*)d_in[5];
    const float* pe = (const float*)d_in[6];
    float* out = (float*)d_out;

    unsigned short* xq_bf = (unsigned short*)d_ws;        // 4096*256   (2 MB)
    unsigned short* WqkT  = xq_bf + (size_t)4096 * C;     // 512*256    (256 KB)
    unsigned short* Qbf   = WqkT + (size_t)512 * C;       // HB*L*D     (2 MB)
    unsigned short* Kbf   = Qbf + (size_t)HB * L * D;     // HB*L*D     (2 MB)
    float* Vo = (float*)(Kbf + (size_t)HB * L * D);       // HB*L f32
    float* G  = Vo + (size_t)HB * L;
    float* S  = G  + (size_t)HB * L;

    prep_kernel<<<256, 256, 0, stream>>>(x, Wq, Wk, Wv, pe, xq_bf, WqkT, Vo);
    qkgemm_kernel<<<512, 256, 0, stream>>>(
        (const __bf16*)xq_bf, (const __bf16*)WqkT, bq, bk, Qbf, Kbf);
    passA_kernel<<<HB * (L / 32), 256, 0, stream>>>(
        (const __bf16*)Qbf, (const __bf16*)Kbf, Vo, G);
    passB_kernel<<<HB * (L / 16), 256, 0, stream>>>(
        (const __bf16*)Qbf, (const __bf16*)Kbf, G, S);
    pool_kernel<<<(B * L * H) / 256, 256, 0, stream>>>(S, out);
}